// Round 1
// baseline (427.219 us; speedup 1.0000x reference)
//
#include <hip/hip_runtime.h>

// TargetAttention: B=4096, L=200, D=64, fp32.
// out[b] = (softmax_l( (tk[b]@Wt^T@Wi) . ik[b,l] / 8 + maskbias ) . iv[b,l,:]) @ Wv^T
// One block of 256 threads per batch row. Memory-bound: streams ik+iv (419 MB).

#define B_ 4096
#define L_ 200
#define D_ 64

__global__ __launch_bounds__(256) void ta_kernel(
    const float* __restrict__ tk,    // [B,D]
    const float* __restrict__ ik,    // [B,L,D]
    const float* __restrict__ iv,    // [B,L,D]
    const int*   __restrict__ mask,  // [B,L]
    const float* __restrict__ Wt,    // [D,D]
    const float* __restrict__ Wi,    // [D,D]
    const float* __restrict__ Wv,    // [D,D]
    float* __restrict__ out)         // [B,D]
{
  const int t = threadIdx.x;
  const int b = blockIdx.x;

  __shared__ float q_s[D_];
  __shared__ float qt_s[D_];
  __shared__ float sc[L_];
  __shared__ float red[8];
  __shared__ float vred[256 * 4];
  __shared__ float sv[D_];

  // ---- phase 0: qt = (tk[b] @ Wt^T) @ Wi  (weights are L1/L2-hot) ----
  if (t < D_) {
    const float* tkb = tk + (size_t)b * D_;
    float a = 0.f;
#pragma unroll
    for (int d = 0; d < D_; ++d) a += tkb[d] * Wt[t * D_ + d];
    q_s[t] = a;
  }
  __syncthreads();
  if (t < D_) {
    float a = 0.f;
#pragma unroll
    for (int e = 0; e < D_; ++e) a += q_s[e] * Wi[e * D_ + t];
    qt_s[t] = a;
  }
  __syncthreads();

  // ---- phase 1: scores[l] = qt . ik[b,l] / 8 + mask bias ----
  const float4* ik4 = (const float4*)(ik + (size_t)b * (L_ * D_));
  const float4* q4  = (const float4*)qt_s;
  if (t < L_) {
    float p = 0.f;
#pragma unroll
    for (int j = 0; j < 16; ++j) {
      float4 kv = ik4[t * 16 + j];   // lane-private row, stride-256B; L1 absorbs
      float4 qq = q4[j];             // LDS broadcast, conflict-free
      p += kv.x * qq.x + kv.y * qq.y + kv.z * qq.z + kv.w * qq.w;
    }
    float m = (float)mask[(size_t)b * L_ + t];
    sc[t] = p * 0.125f - 1e8f * (1.0f - m);
  }
  __syncthreads();

  // ---- softmax over L=200 (wave shuffle + LDS combine) ----
  float v = (t < L_) ? sc[t] : -3.0e38f;
#pragma unroll
  for (int off = 32; off >= 1; off >>= 1)
    v = fmaxf(v, __shfl_xor(v, off, 64));
  if ((t & 63) == 0) red[t >> 6] = v;
  __syncthreads();
  float mx = fmaxf(fmaxf(red[0], red[1]), fmaxf(red[2], red[3]));
  float ex = (t < L_) ? expf(sc[t] - mx) : 0.f;
  float s = ex;
#pragma unroll
  for (int off = 32; off >= 1; off >>= 1)
    s += __shfl_xor(s, off, 64);
  if ((t & 63) == 0) red[4 + (t >> 6)] = s;
  __syncthreads();
  float tot = red[4] + red[5] + red[6] + red[7];
  if (t < L_) sc[t] = ex / tot;   // normalized weights
  __syncthreads();

  // ---- phase 2: sv[d] = sum_l w[l] * iv[b,l,d]  (coalesced 4KB/iter) ----
  const float4* iv4 = (const float4*)(iv + (size_t)b * (L_ * D_));
  const int c = t & 15;        // float4 chunk of D (d in [4c,4c+4))
  const int rg = t >> 4;       // row group 0..15
  float4 acc = make_float4(0.f, 0.f, 0.f, 0.f);
#pragma unroll
  for (int it = 0; it < 13; ++it) {
    int row = it * 16 + rg;
    if (row < L_) {
      float w = sc[row];
      float4 vv = iv4[row * 16 + c];   // block reads iv4[it*256 + t]: contiguous
      acc.x += w * vv.x; acc.y += w * vv.y;
      acc.z += w * vv.z; acc.w += w * vv.w;
    }
  }
  ((float4*)vred)[t] = acc;
  __syncthreads();
  if (t < D_) {
    float a = 0.f;
#pragma unroll
    for (int rg2 = 0; rg2 < 16; ++rg2) a += vred[rg2 * 64 + t];  // conflict-free
    sv[t] = a;
  }
  __syncthreads();

  // ---- phase 3: out[b,e] = sv @ Wv^T  (Wv is L1-hot) ----
  if (t < D_) {
    const float4* Wv4 = (const float4*)Wv;
    const float4* sv4 = (const float4*)sv;
    float a = 0.f;
#pragma unroll
    for (int cc = 0; cc < 16; ++cc) {
      float4 w4 = Wv4[t * 16 + cc];
      float4 s4 = sv4[cc];
      a += w4.x * s4.x + w4.y * s4.y + w4.z * s4.z + w4.w * s4.w;
    }
    out[(size_t)b * D_ + t] = a;
  }
}

extern "C" void kernel_launch(void* const* d_in, const int* in_sizes, int n_in,
                              void* d_out, int out_size, void* d_ws, size_t ws_size,
                              hipStream_t stream) {
  const float* tk   = (const float*)d_in[0];  // target_key  [B,D]
  const float* ik   = (const float*)d_in[1];  // item_keys   [B,L,D]
  const float* iv   = (const float*)d_in[2];  // item_values [B,L,D]
  const int*   mask = (const int*)  d_in[3];  // mask        [B,L]
  const float* Wt   = (const float*)d_in[4];  // W_target    [D,D]
  const float* Wi   = (const float*)d_in[5];  // W_item      [D,D]
  const float* Wv   = (const float*)d_in[6];  // W_value     [D,D]
  float* out = (float*)d_out;                 // [B,D]

  ta_kernel<<<B_, 256, 0, stream>>>(tk, ik, iv, mask, Wt, Wi, Wv, out);
}